// Round 10
// baseline (484.727 us; speedup 1.0000x reference)
//
#include <hip/hip_runtime.h>

typedef unsigned short u16;
typedef unsigned int   u32;

typedef short short8 __attribute__((ext_vector_type(8)));
typedef float floatx4 __attribute__((ext_vector_type(4)));

#define CDIM 128
#define K_NEG_LOG2E -1.4426950408889634f
#define CNT_SCALE 16777216.0   // 2^24: packs (sum, count) into one f64
#define NBUCK 4096             // 64x64 Morton buckets (si>>10, ii>>9)
#define HBLK 128               // histogram / scatter blocks

__device__ __forceinline__ float bf2f_lo(u32 h) {
    union { u32 u; float f; } v; v.u = h << 16; return v.f;
}
__device__ __forceinline__ float bf2f_hi(u32 h) {
    union { u32 u; float f; } v; v.u = h & 0xffff0000u; return v.f;
}
__device__ __forceinline__ u16 f2bf(float f) {
    union { float f; u32 u; } v; v.f = f;
    u32 u = v.u;
    return (u16)((u + 0x7FFFu + ((u >> 16) & 1u)) >> 16);  // RNE
}
__device__ __forceinline__ float sig_std(float x) {
    return __builtin_amdgcn_rcpf(1.0f + __builtin_amdgcn_exp2f(x * K_NEG_LOG2E));
}
// Morton-interleave two 6-bit bucket ids -> 12-bit key.
__device__ __forceinline__ u32 mkey(u32 si, u32 ii) {
    u32 a = si >> 10, b = ii >> 9, k = 0;
#pragma unroll
    for (int i = 0; i < 6; ++i) {
        k |= ((a >> i) & 1u) << (2 * i + 1);
        k |= ((b >> i) & 1u) << (2 * i);
    }
    return k;
}

// Zero f64 accumulators + convert weights to pre-scaled bf16. NO atomics.
__global__ __launch_bounds__(256) void prep_kernel(
    const float* __restrict__ Wstu, const float* __restrict__ Witem,
    u32* __restrict__ Wbf_pair, float4* __restrict__ zero4, int nZero4)
{
    const int tid = blockIdx.x * blockDim.x + threadIdx.x;
    const int stride = gridDim.x * blockDim.x;
    for (int i = tid; i < 16384; i += stride) {
        const float* W = (i & 8192) ? (Witem - 16384) : Wstu;
        const int j = i * 2;
        u32 lo = f2bf(W[j]     * K_NEG_LOG2E);
        u32 hi = f2bf(W[j + 1] * K_NEG_LOG2E);
        Wbf_pair[i] = lo | (hi << 16);
    }
    const float4 z = {0.f, 0.f, 0.f, 0.f};
    for (int i = tid; i < nZero4; i += stride) zero4[i] = z;
}

// Per-block LDS histogram -> lhists[b][NBUCK]. Zero global atomics.
__global__ __launch_bounds__(256) void hist_kernel(
    const int* __restrict__ stu_track, const int* __restrict__ item_index,
    u32* __restrict__ lhists, int E)
{
    __shared__ u32 h[NBUCK];
    for (int k = threadIdx.x; k < NBUCK; k += 256) h[k] = 0;
    __syncthreads();
    const int chunk = (E + gridDim.x - 1) / gridDim.x;
    const int s = blockIdx.x * chunk;
    const int e = min(E, s + chunk);
    for (int i = s + threadIdx.x; i < e; i += 256)
        atomicAdd(&h[mkey((u32)stu_track[i], (u32)item_index[i])], 1u);
    __syncthreads();
    u32* out = lhists + (size_t)blockIdx.x * NBUCK;
    for (int k = threadIdx.x; k < NBUCK; k += 256) out[k] = h[k];
}

// Sum lhists across HBLK blocks, exclusive prefix -> cursor[NBUCK].
__global__ __launch_bounds__(256) void prefix_kernel(
    const u32* __restrict__ lhists, u32* __restrict__ cursor)
{
    __shared__ u32 psum[256];
    const int t = threadIdx.x;
    const int PER = NBUCK / 256;   // 16
    u32 tot[PER];
#pragma unroll
    for (int j = 0; j < PER; ++j) {
        u32 s = 0;
        for (int b = 0; b < HBLK; ++b)
            s += lhists[(size_t)b * NBUCK + t * PER + j];
        tot[j] = s;
    }
    u32 s = 0;
#pragma unroll
    for (int j = 0; j < PER; ++j) s += tot[j];
    psum[t] = s;
    __syncthreads();
    for (int off = 1; off < 256; off <<= 1) {
        u32 add = (t >= off) ? psum[t - off] : 0;
        __syncthreads();
        psum[t] += add;
        __syncthreads();
    }
    u32 run = (t > 0) ? psum[t - 1] : 0;
#pragma unroll
    for (int j = 0; j < PER; ++j) {
        cursor[t * PER + j] = run;
        run += tot[j];
    }
}

// Counting-sort scatter: pack {stu,item,conc,mean} byte offsets into idx4 at
// the Morton-sorted position. LDS two-pass per block chunk; one atomic
// reservation per (block, nonempty bucket).
__global__ __launch_bounds__(256) void scatter_kernel(
    const int* __restrict__ stu_track, const int* __restrict__ item_index,
    const int* __restrict__ conc_index, const int* __restrict__ mean_index,
    u32* __restrict__ cursor, int4* __restrict__ idx4, int E)
{
    __shared__ u32 lhist[NBUCK];
    __shared__ u32 lbase[NBUCK];
    const int chunk = (E + gridDim.x - 1) / gridDim.x;
    const int start = blockIdx.x * chunk;
    const int end   = min(E, start + chunk);

    for (int k = threadIdx.x; k < NBUCK; k += blockDim.x) lhist[k] = 0;
    __syncthreads();
    for (int e = start + threadIdx.x; e < end; e += blockDim.x)
        atomicAdd(&lhist[mkey((u32)stu_track[e], (u32)item_index[e])], 1u);
    __syncthreads();
    for (int k = threadIdx.x; k < NBUCK; k += blockDim.x) {
        const u32 c = lhist[k];
        lbase[k] = c ? atomicAdd(&cursor[k], c) : 0u;
        lhist[k] = 0;
    }
    __syncthreads();
    for (int e = start + threadIdx.x; e < end; e += blockDim.x) {
        const u32 si = (u32)stu_track[e], ii = (u32)item_index[e];
        const u32 k = mkey(si, ii);
        const u32 pos = lbase[k] + atomicAdd(&lhist[k], 1u);
        int4 t;
        t.x = (int)(si << 8);              // 256 B rows
        t.y = (int)(ii << 8);              // 256 B rows
        t.z = conc_index[e] << 9;          // 512 B rows (cat)
        t.w = mean_index[e] << 3;          // f64 slots
        idx4[pos] = t;
    }
}

// One wave computes a 32-row tile; stores exp2(proj + bias) in bf16.
__device__ __forceinline__ void proj_tile32(
    const float* __restrict__ X, const u16* __restrict__ Wbf,
    const float* __restrict__ bias, u16* __restrict__ out,
    int nrows, int ostride, int ooff, int row0, int lane)
{
    const int m = lane & 15;   // A-row / B-col / D-col
    const int g = lane >> 4;   // k-quad

    short8 a[2][4];
#pragma unroll
    for (int t = 0; t < 2; ++t) {
        int arow = row0 + t * 16 + m;
        if (arow >= nrows) arow = nrows - 1;   // clamp; stores masked below
        const float* xrow = X + (size_t)arow * CDIM;
#pragma unroll
        for (int s = 0; s < 4; ++s) {
            float4 f0 = *(const float4*)(xrow + s * 32 + g * 8);
            float4 f1 = *(const float4*)(xrow + s * 32 + g * 8 + 4);
            a[t][s][0] = (short)f2bf(f0.x); a[t][s][1] = (short)f2bf(f0.y);
            a[t][s][2] = (short)f2bf(f0.z); a[t][s][3] = (short)f2bf(f0.w);
            a[t][s][4] = (short)f2bf(f1.x); a[t][s][5] = (short)f2bf(f1.y);
            a[t][s][6] = (short)f2bf(f1.z); a[t][s][7] = (short)f2bf(f1.w);
        }
    }

#pragma unroll
    for (int ct = 0; ct < 8; ++ct) {
        const u16* wrow = Wbf + (size_t)(ct * 16 + m) * CDIM;
        floatx4 acc0 = {0.f, 0.f, 0.f, 0.f};
        floatx4 acc1 = {0.f, 0.f, 0.f, 0.f};
#pragma unroll
        for (int s = 0; s < 4; ++s) {
            short8 b = *(const short8*)(wrow + s * 32 + g * 8);
            acc0 = __builtin_amdgcn_mfma_f32_16x16x32_bf16(a[0][s], b, acc0, 0, 0, 0);
            acc1 = __builtin_amdgcn_mfma_f32_16x16x32_bf16(a[1][s], b, acc1, 0, 0, 0);
        }
        const int col = ct * 16 + m;           // D: col = lane&15
        const float badd = bias ? bias[col] * K_NEG_LOG2E : 0.f;
#pragma unroll
        for (int i = 0; i < 4; ++i) {
            int r0 = row0 + g * 4 + i;         // D: row = (lane>>4)*4 + reg
            if (r0 < nrows)
                out[(size_t)r0 * ostride + ooff + col] =
                    f2bf(__builtin_amdgcn_exp2f(acc0[i] + badd));
            int r1 = r0 + 16;
            if (r1 < nrows)
                out[(size_t)r1 * ostride + ooff + col] =
                    f2bf(__builtin_amdgcn_exp2f(acc1[i] + badd));
        }
    }
}

// All four projections in one launch; wave-uniform segment select.
__global__ __launch_bounds__(256) void proj4_kernel(
    const float* __restrict__ stu_x, const float* __restrict__ item_x,
    const float* __restrict__ conc_x,
    const u16* __restrict__ Wstu_bf, const u16* __restrict__ Witem_bf,
    const float* __restrict__ b_stu, const float* __restrict__ b_item,
    u16* __restrict__ stu_p, u16* __restrict__ item_p, u16* __restrict__ conc_cat,
    int NS, int NI, int NC)
{
    const int lane = threadIdx.x & 63;
    int w = blockIdx.x * 4 + (threadIdx.x >> 6);
    const int T0 = (NS + 31) / 32, T1 = (NI + 31) / 32, T2 = (NC + 31) / 32;

    if (w < T0) { proj_tile32(stu_x, Wstu_bf, nullptr, stu_p, NS, 128, 0, w * 32, lane); return; }
    w -= T0;
    if (w < T1) { proj_tile32(item_x, Witem_bf, nullptr, item_p, NI, 128, 0, w * 32, lane); return; }
    w -= T1;
    if (w < T2) { proj_tile32(conc_x, Wstu_bf, b_stu, conc_cat, NC, 256, 0, w * 32, lane); return; }
    w -= T2;
    if (w < T2) { proj_tile32(conc_x, Witem_bf, b_item, conc_cat, NC, 256, 128, w * 32, lane); return; }
}

// 16 lanes per edge, 4 edges per wave, depth-1 pipeline. idx4 is Morton-
// sorted; 512 blocks (2/CU resident) keep the chip-wide grid-stride window
// at ~8K edges -> ~1.8 MB working set -> L2-resident gathers.
__global__ __launch_bounds__(256) void edge_kernel(
    const u16* __restrict__ stu_p, const u16* __restrict__ item_p,
    const u16* __restrict__ conc_cat,
    const int4* __restrict__ idx4,     // byte offsets {stu, item, conc, mean}
    const float* __restrict__ w_pred,
    double* __restrict__ sc, int E)
{
    const int lane = threadIdx.x & 63;
    const int sub  = lane & 15;      // position within edge
    const int g    = lane >> 4;      // edge within quad
    const int waveId = (int)((blockIdx.x * blockDim.x + threadIdx.x) >> 6);
    const int S      = (int)((gridDim.x * blockDim.x) >> 6);   // wave stride

    const float4 wA = ((const float4*)w_pred)[sub * 2];
    const float4 wB = ((const float4*)w_pred)[sub * 2 + 1];
    float2 w2[4];
    w2[0] = make_float2(wA.x, wA.y); w2[1] = make_float2(wA.z, wA.w);
    w2[2] = make_float2(wB.x, wB.y); w2[3] = make_float2(wB.z, wB.w);
    const u32 lane_off = (u32)sub * 16;

    const int nQuads = (E + 3) >> 2;
    int q = waveId;
    if (q >= nQuads) return;

    auto ldidx = [&](int qq) -> int4 {
        int e = qq * 4 + g;
        e = (e < E) ? e : (E - 1);
        return idx4[e];
    };
    auto compute = [&](const uint4& sv, const uint4& iv,
                       const uint4& ca, const uint4& cb,
                       int mw, int qq) {
        const u32 su[4] = {sv.x, sv.y, sv.z, sv.w};
        const u32 iu[4] = {iv.x, iv.y, iv.z, iv.w};
        const u32 au[4] = {ca.x, ca.y, ca.z, ca.w};
        const u32 bu[4] = {cb.x, cb.y, cb.z, cb.w};
        const float2 one = make_float2(1.f, 1.f);
        float2 vacc = make_float2(0.f, 0.f);
#pragma unroll
        for (int j = 0; j < 4; ++j) {
            float2 A  = make_float2(bf2f_lo(au[j]), bf2f_hi(au[j]));
            float2 Sx = make_float2(bf2f_lo(su[j]), bf2f_hi(su[j]));
            float2 B  = make_float2(bf2f_lo(bu[j]), bf2f_hi(bu[j]));
            float2 Ix = make_float2(bf2f_lo(iu[j]), bf2f_hi(iu[j]));
            float2 ea = A * Sx;                    // v_pk_mul_f32
            float2 eb = B * Ix;
            float2 den = (ea + one) * (eb + one);  // (1+ea)(1+eb)
            float2 num = eb - ea;
            float2 rd = make_float2(__builtin_amdgcn_rcpf(den.x),
                                    __builtin_amdgcn_rcpf(den.y));
            vacc += (num * rd) * w2[j];
        }
        float v = vacc.x + vacc.y;
        v += __shfl_xor(v, 1, 64);
        v += __shfl_xor(v, 2, 64);
        v += __shfl_xor(v, 4, 64);
        v += __shfl_xor(v, 8, 64);
        if (sub == 0 && (qq * 4 + g) < E)
            atomicAdd((double*)((char*)sc + (u32)mw), (double)v + CNT_SCALE);
    };

#define GATH(I_, sv_, iv_, ca_, cb_) { \
        sv_ = *(const uint4*)((const char*)stu_p  + ((u32)(I_).x + lane_off)); \
        iv_ = *(const uint4*)((const char*)item_p + ((u32)(I_).y + lane_off)); \
        const char* cp_ = (const char*)conc_cat + ((u32)(I_).z + lane_off); \
        ca_ = *(const uint4*)cp_; cb_ = *(const uint4*)(cp_ + 256); }

#define STEP(DA, DB, IA, IB, IC) { \
        GATH(I##IB, sv##DB, iv##DB, ca##DB, cb##DB); \
        I##IC = ldidx(q + 2 * S); \
        __builtin_amdgcn_sched_barrier(0x7); \
        compute(sv##DA, iv##DA, ca##DA, cb##DA, I##IA.w, q); \
        q += S; \
        if (q >= nQuads) break; }

    // preamble
    int4 I0 = ldidx(q), I1 = ldidx(q + S), I2, I3;
    uint4 sv0, iv0, ca0, cb0, sv1, iv1, ca1, cb1;
    GATH(I0, sv0, iv0, ca0, cb0);

    for (;;) {
        STEP(0, 1, 0, 1, 2)
        STEP(1, 0, 1, 2, 3)
        STEP(0, 1, 2, 3, 0)
        STEP(1, 0, 3, 0, 1)
    }
#undef STEP
#undef GATH
}

__global__ __launch_bounds__(256) void final_kernel(
    const double* __restrict__ sc,
    const float* __restrict__ b_pred, float* __restrict__ out, int M)
{
    const int i = blockIdx.x * blockDim.x + threadIdx.x;
    if (i < M) {
        const double acc = sc[i];
        const double cnt = rint(acc * (1.0 / CNT_SCALE));   // |sum| << 2^23
        const double sum = acc - cnt * CNT_SCALE;
        const float mean = (float)(sum / fmax(cnt, 1.0));
        out[i] = sig_std(mean + b_pred[0]);
    }
}

extern "C" void kernel_launch(void* const* d_in, const int* in_sizes, int n_in,
                              void* d_out, int out_size, void* d_ws, size_t ws_size,
                              hipStream_t stream) {
    const float* stu_x    = (const float*)d_in[0];
    const float* item_x   = (const float*)d_in[1];
    const float* conc_x   = (const float*)d_in[2];
    const float* W_stu    = (const float*)d_in[3];
    const float* b_stu    = (const float*)d_in[4];
    const float* W_item   = (const float*)d_in[5];
    const float* b_item   = (const float*)d_in[6];
    const float* W_pred   = (const float*)d_in[7];
    const float* b_pred   = (const float*)d_in[8];
    const int* stu_track  = (const int*)d_in[9];
    const int* item_index = (const int*)d_in[10];
    const int* conc_index = (const int*)d_in[11];
    const int* mean_index = (const int*)d_in[12];

    const int NS = in_sizes[0] / CDIM;
    const int NI = in_sizes[1] / CDIM;
    const int NC = in_sizes[2] / CDIM;
    const int E  = in_sizes[9];
    const int M  = out_size;

    // workspace layout (all pieces 16B-aligned)
    double* sc     = (double*)d_ws;              // [M] packed (sum + cnt*2^24)
    u16* Wstu_bf   = (u16*)(sc + M);             // Wstu_bf || Witem_bf contiguous
    u16* Witem_bf  = Wstu_bf + CDIM * CDIM;
    u16* stu_p     = Witem_bf + CDIM * CDIM;
    u16* item_p    = stu_p  + (size_t)NS * CDIM;
    u16* conc_cat  = item_p + (size_t)NI * CDIM; // [NC][256]: exp2 stu | item side
    int4* idx4     = (int4*)(conc_cat + (size_t)NC * 256);
    u32* lhists    = (u32*)(idx4 + E);           // [HBLK][NBUCK]
    u32* cursor    = lhists + (size_t)HBLK * NBUCK;

    const int nZero4 = (int)(((size_t)M * sizeof(double)) / 16);
    prep_kernel<<<512, 256, 0, stream>>>(W_stu, W_item, (u32*)Wstu_bf,
                                         (float4*)sc, nZero4);

    hist_kernel<<<HBLK, 256, 0, stream>>>(stu_track, item_index, lhists, E);

    prefix_kernel<<<1, 256, 0, stream>>>(lhists, cursor);

    scatter_kernel<<<HBLK, 256, 0, stream>>>(stu_track, item_index, conc_index,
                                             mean_index, cursor, idx4, E);

    const int T0 = (NS + 31) / 32, T1 = (NI + 31) / 32, T2 = (NC + 31) / 32;
    const int totalWaves = T0 + T1 + 2 * T2;
    proj4_kernel<<<(totalWaves + 3) / 4, 256, 0, stream>>>(
        stu_x, item_x, conc_x, Wstu_bf, Witem_bf, b_stu, b_item,
        stu_p, item_p, conc_cat, NS, NI, NC);

    edge_kernel<<<512, 256, 0, stream>>>(stu_p, item_p, conc_cat,
                                         idx4, W_pred, sc, E);

    final_kernel<<<(M + 255) / 256, 256, 0, stream>>>(sc, b_pred, (float*)d_out, M);
}

// Round 11
// 262.841 us; speedup vs baseline: 1.8442x; 1.8442x over previous
//
#include <hip/hip_runtime.h>

typedef unsigned short u16;
typedef unsigned int   u32;

typedef short short8 __attribute__((ext_vector_type(8)));
typedef float floatx4 __attribute__((ext_vector_type(4)));

#define CDIM 128
#define K_NEG_LOG2E -1.4426950408889634f
#define CNT_SCALE 16777216.0   // 2^24: packs (sum, count) into one f64
#define NBUCK 4096             // si>>4 buckets (NS=50K -> 3125 used)
#define HBLK 128               // histogram / scatter blocks

__device__ __forceinline__ float bf2f_lo(u32 h) {
    union { u32 u; float f; } v; v.u = h << 16; return v.f;
}
__device__ __forceinline__ float bf2f_hi(u32 h) {
    union { u32 u; float f; } v; v.u = h & 0xffff0000u; return v.f;
}
__device__ __forceinline__ u16 f2bf(float f) {
    union { float f; u32 u; } v; v.f = f;
    u32 u = v.u;
    return (u16)((u + 0x7FFFu + ((u >> 16) & 1u)) >> 16);  // RNE
}
__device__ __forceinline__ float sig_std(float x) {
    return __builtin_amdgcn_rcpf(1.0f + __builtin_amdgcn_exp2f(x * K_NEG_LOG2E));
}
// sort key: stu-row group of 16 -> contiguous edges share a tiny stu footprint
__device__ __forceinline__ u32 skey(u32 si) { return si >> 4; }

// Zero f64 accumulators + convert weights to pre-scaled bf16. NO atomics.
__global__ __launch_bounds__(256) void prep_kernel(
    const float* __restrict__ Wstu, const float* __restrict__ Witem,
    u32* __restrict__ Wbf_pair, float4* __restrict__ zero4, int nZero4)
{
    const int tid = blockIdx.x * blockDim.x + threadIdx.x;
    const int stride = gridDim.x * blockDim.x;
    for (int i = tid; i < 16384; i += stride) {
        const float* W = (i & 8192) ? (Witem - 16384) : Wstu;
        const int j = i * 2;
        u32 lo = f2bf(W[j]     * K_NEG_LOG2E);
        u32 hi = f2bf(W[j + 1] * K_NEG_LOG2E);
        Wbf_pair[i] = lo | (hi << 16);
    }
    const float4 z = {0.f, 0.f, 0.f, 0.f};
    for (int i = tid; i < nZero4; i += stride) zero4[i] = z;
}

// Per-block LDS histogram -> lhists[b][NBUCK]. Zero global atomics.
__global__ __launch_bounds__(256) void hist_kernel(
    const int* __restrict__ stu_track, u32* __restrict__ lhists, int E)
{
    __shared__ u32 h[NBUCK];
    for (int k = threadIdx.x; k < NBUCK; k += 256) h[k] = 0;
    __syncthreads();
    const int chunk = (E + gridDim.x - 1) / gridDim.x;
    const int s = blockIdx.x * chunk;
    const int e = min(E, s + chunk);
    for (int i = s + threadIdx.x; i < e; i += 256)
        atomicAdd(&h[skey((u32)stu_track[i])], 1u);
    __syncthreads();
    u32* out = lhists + (size_t)blockIdx.x * NBUCK;
    for (int k = threadIdx.x; k < NBUCK; k += 256) out[k] = h[k];
}

// One thread per bucket: convert lhists[:,k] to exclusive prefix over blocks
// (deterministic per-block scatter bases) and emit the bucket total.
__global__ __launch_bounds__(256) void reduce_kernel(
    u32* __restrict__ lhists, u32* __restrict__ tot)
{
    const int k = blockIdx.x * blockDim.x + threadIdx.x;
    if (k >= NBUCK) return;
    u32 run = 0;
    for (int b = 0; b < HBLK; ++b) {
        u32* p = lhists + (size_t)b * NBUCK + k;
        const u32 c = *p;
        *p = run;          // exclusive over blocks
        run += c;
    }
    tot[k] = run;
}

// Single block: exclusive prefix over NBUCK totals -> cursor.
__global__ __launch_bounds__(256) void scan_kernel(
    const u32* __restrict__ tot, u32* __restrict__ cursor)
{
    __shared__ u32 psum[256];
    const int t = threadIdx.x;
    const int PER = NBUCK / 256;   // 16
    u32 loc[PER];
    u32 s = 0;
#pragma unroll
    for (int j = 0; j < PER; ++j) { loc[j] = tot[t * PER + j]; s += loc[j]; }
    psum[t] = s;
    __syncthreads();
    for (int off = 1; off < 256; off <<= 1) {
        u32 add = (t >= off) ? psum[t - off] : 0;
        __syncthreads();
        psum[t] += add;
        __syncthreads();
    }
    u32 run = (t > 0) ? psum[t - 1] : 0;
#pragma unroll
    for (int j = 0; j < PER; ++j) {
        cursor[t * PER + j] = run;
        run += loc[j];
    }
}

// Counting-sort scatter, fully deterministic (zero global atomics):
// base = cursor[k] + lhists_excl[block][k]; within-block order via LDS atomics.
__global__ __launch_bounds__(256) void scatter_kernel(
    const int* __restrict__ stu_track, const int* __restrict__ item_index,
    const int* __restrict__ conc_index, const int* __restrict__ mean_index,
    const u32* __restrict__ cursor, const u32* __restrict__ lhists,
    int4* __restrict__ idx4, int E)
{
    __shared__ u32 lbase[NBUCK];
    const u32* myoff = lhists + (size_t)blockIdx.x * NBUCK;
    for (int k = threadIdx.x; k < NBUCK; k += blockDim.x)
        lbase[k] = cursor[k] + myoff[k];
    __syncthreads();
    const int chunk = (E + gridDim.x - 1) / gridDim.x;
    const int start = blockIdx.x * chunk;
    const int end   = min(E, start + chunk);
    for (int e = start + threadIdx.x; e < end; e += blockDim.x) {
        const u32 si = (u32)stu_track[e];
        const u32 pos = atomicAdd(&lbase[skey(si)], 1u);
        int4 t;
        t.x = (int)(si << 8);              // 256 B rows
        t.y = item_index[e] << 8;          // 256 B rows
        t.z = conc_index[e] << 9;          // 512 B rows (cat)
        t.w = mean_index[e] << 3;          // f64 slots
        idx4[pos] = t;
    }
}

// One wave computes a 32-row tile; stores exp2(proj + bias) in bf16.
__device__ __forceinline__ void proj_tile32(
    const float* __restrict__ X, const u16* __restrict__ Wbf,
    const float* __restrict__ bias, u16* __restrict__ out,
    int nrows, int ostride, int ooff, int row0, int lane)
{
    const int m = lane & 15;   // A-row / B-col / D-col
    const int g = lane >> 4;   // k-quad

    short8 a[2][4];
#pragma unroll
    for (int t = 0; t < 2; ++t) {
        int arow = row0 + t * 16 + m;
        if (arow >= nrows) arow = nrows - 1;   // clamp; stores masked below
        const float* xrow = X + (size_t)arow * CDIM;
#pragma unroll
        for (int s = 0; s < 4; ++s) {
            float4 f0 = *(const float4*)(xrow + s * 32 + g * 8);
            float4 f1 = *(const float4*)(xrow + s * 32 + g * 8 + 4);
            a[t][s][0] = (short)f2bf(f0.x); a[t][s][1] = (short)f2bf(f0.y);
            a[t][s][2] = (short)f2bf(f0.z); a[t][s][3] = (short)f2bf(f0.w);
            a[t][s][4] = (short)f2bf(f1.x); a[t][s][5] = (short)f2bf(f1.y);
            a[t][s][6] = (short)f2bf(f1.z); a[t][s][7] = (short)f2bf(f1.w);
        }
    }

#pragma unroll
    for (int ct = 0; ct < 8; ++ct) {
        const u16* wrow = Wbf + (size_t)(ct * 16 + m) * CDIM;
        floatx4 acc0 = {0.f, 0.f, 0.f, 0.f};
        floatx4 acc1 = {0.f, 0.f, 0.f, 0.f};
#pragma unroll
        for (int s = 0; s < 4; ++s) {
            short8 b = *(const short8*)(wrow + s * 32 + g * 8);
            acc0 = __builtin_amdgcn_mfma_f32_16x16x32_bf16(a[0][s], b, acc0, 0, 0, 0);
            acc1 = __builtin_amdgcn_mfma_f32_16x16x32_bf16(a[1][s], b, acc1, 0, 0, 0);
        }
        const int col = ct * 16 + m;           // D: col = lane&15
        const float badd = bias ? bias[col] * K_NEG_LOG2E : 0.f;
#pragma unroll
        for (int i = 0; i < 4; ++i) {
            int r0 = row0 + g * 4 + i;         // D: row = (lane>>4)*4 + reg
            if (r0 < nrows)
                out[(size_t)r0 * ostride + ooff + col] =
                    f2bf(__builtin_amdgcn_exp2f(acc0[i] + badd));
            int r1 = r0 + 16;
            if (r1 < nrows)
                out[(size_t)r1 * ostride + ooff + col] =
                    f2bf(__builtin_amdgcn_exp2f(acc1[i] + badd));
        }
    }
}

// All four projections in one launch; wave-uniform segment select.
__global__ __launch_bounds__(256) void proj4_kernel(
    const float* __restrict__ stu_x, const float* __restrict__ item_x,
    const float* __restrict__ conc_x,
    const u16* __restrict__ Wstu_bf, const u16* __restrict__ Witem_bf,
    const float* __restrict__ b_stu, const float* __restrict__ b_item,
    u16* __restrict__ stu_p, u16* __restrict__ item_p, u16* __restrict__ conc_cat,
    int NS, int NI, int NC)
{
    const int lane = threadIdx.x & 63;
    int w = blockIdx.x * 4 + (threadIdx.x >> 6);
    const int T0 = (NS + 31) / 32, T1 = (NI + 31) / 32, T2 = (NC + 31) / 32;

    if (w < T0) { proj_tile32(stu_x, Wstu_bf, nullptr, stu_p, NS, 128, 0, w * 32, lane); return; }
    w -= T0;
    if (w < T1) { proj_tile32(item_x, Witem_bf, nullptr, item_p, NI, 128, 0, w * 32, lane); return; }
    w -= T1;
    if (w < T2) { proj_tile32(conc_x, Wstu_bf, b_stu, conc_cat, NC, 256, 0, w * 32, lane); return; }
    w -= T2;
    if (w < T2) { proj_tile32(conc_x, Witem_bf, b_item, conc_cat, NC, 256, 128, w * 32, lane); return; }
}

// 16 lanes per edge, 4 edges per wave. idx4 is si-sorted; each wave owns a
// CONTIGUOUS quad range -> its ~244 edges touch ~8 KB of stu rows (L1-hot),
// freeing L2 for the item table. Depth-1 ping-pong pipeline retained.
__global__ __launch_bounds__(256) void edge_kernel(
    const u16* __restrict__ stu_p, const u16* __restrict__ item_p,
    const u16* __restrict__ conc_cat,
    const int4* __restrict__ idx4,     // byte offsets {stu, item, conc, mean}
    const float* __restrict__ w_pred,
    double* __restrict__ sc, int E)
{
    const int lane = threadIdx.x & 63;
    const int sub  = lane & 15;      // position within edge
    const int g    = lane >> 4;      // edge within quad
    const int waveId = (int)((blockIdx.x * blockDim.x + threadIdx.x) >> 6);
    const int nWavesTot = (int)((gridDim.x * blockDim.x) >> 6);

    const float4 wA = ((const float4*)w_pred)[sub * 2];
    const float4 wB = ((const float4*)w_pred)[sub * 2 + 1];
    float2 w2[4];
    w2[0] = make_float2(wA.x, wA.y); w2[1] = make_float2(wA.z, wA.w);
    w2[2] = make_float2(wB.x, wB.y); w2[3] = make_float2(wB.z, wB.w);
    const u32 lane_off = (u32)sub * 16;

    const int nQuads = (E + 3) >> 2;
    const int chunk  = (nQuads + nWavesTot - 1) / nWavesTot;
    int q = waveId * chunk;
    const int qEnd = min(nQuads, q + chunk);
    if (q >= qEnd) return;

    auto ldidx = [&](int qq) -> int4 {
        int e = qq * 4 + g;
        e = (e < E) ? e : (E - 1);
        return idx4[e];
    };
    auto compute = [&](const uint4& sv, const uint4& iv,
                       const uint4& ca, const uint4& cb,
                       int mw, int qq) {
        const u32 su[4] = {sv.x, sv.y, sv.z, sv.w};
        const u32 iu[4] = {iv.x, iv.y, iv.z, iv.w};
        const u32 au[4] = {ca.x, ca.y, ca.z, ca.w};
        const u32 bu[4] = {cb.x, cb.y, cb.z, cb.w};
        const float2 one = make_float2(1.f, 1.f);
        float2 vacc = make_float2(0.f, 0.f);
#pragma unroll
        for (int j = 0; j < 4; ++j) {
            float2 A  = make_float2(bf2f_lo(au[j]), bf2f_hi(au[j]));
            float2 Sx = make_float2(bf2f_lo(su[j]), bf2f_hi(su[j]));
            float2 B  = make_float2(bf2f_lo(bu[j]), bf2f_hi(bu[j]));
            float2 Ix = make_float2(bf2f_lo(iu[j]), bf2f_hi(iu[j]));
            float2 ea = A * Sx;                    // v_pk_mul_f32
            float2 eb = B * Ix;
            float2 den = (ea + one) * (eb + one);  // (1+ea)(1+eb)
            float2 num = eb - ea;
            float2 rd = make_float2(__builtin_amdgcn_rcpf(den.x),
                                    __builtin_amdgcn_rcpf(den.y));
            vacc += (num * rd) * w2[j];
        }
        float v = vacc.x + vacc.y;
        v += __shfl_xor(v, 1, 64);
        v += __shfl_xor(v, 2, 64);
        v += __shfl_xor(v, 4, 64);
        v += __shfl_xor(v, 8, 64);
        if (sub == 0 && (qq * 4 + g) < E)
            atomicAdd((double*)((char*)sc + (u32)mw), (double)v + CNT_SCALE);
    };

#define GATH(I_, sv_, iv_, ca_, cb_) { \
        sv_ = *(const uint4*)((const char*)stu_p  + ((u32)(I_).x + lane_off)); \
        iv_ = *(const uint4*)((const char*)item_p + ((u32)(I_).y + lane_off)); \
        const char* cp_ = (const char*)conc_cat + ((u32)(I_).z + lane_off); \
        ca_ = *(const uint4*)cp_; cb_ = *(const uint4*)(cp_ + 256); }

#define STEP(DA, DB, IA, IB, IC) { \
        GATH(I##IB, sv##DB, iv##DB, ca##DB, cb##DB); \
        I##IC = ldidx(q + 2); \
        __builtin_amdgcn_sched_barrier(0x7); \
        compute(sv##DA, iv##DA, ca##DA, cb##DA, I##IA.w, q); \
        q += 1; \
        if (q >= qEnd) break; }

    // preamble
    int4 I0 = ldidx(q), I1 = ldidx(q + 1), I2, I3;
    uint4 sv0, iv0, ca0, cb0, sv1, iv1, ca1, cb1;
    GATH(I0, sv0, iv0, ca0, cb0);

    for (;;) {
        STEP(0, 1, 0, 1, 2)
        STEP(1, 0, 1, 2, 3)
        STEP(0, 1, 2, 3, 0)
        STEP(1, 0, 3, 0, 1)
    }
#undef STEP
#undef GATH
}

__global__ __launch_bounds__(256) void final_kernel(
    const double* __restrict__ sc,
    const float* __restrict__ b_pred, float* __restrict__ out, int M)
{
    const int i = blockIdx.x * blockDim.x + threadIdx.x;
    if (i < M) {
        const double acc = sc[i];
        const double cnt = rint(acc * (1.0 / CNT_SCALE));   // |sum| << 2^23
        const double sum = acc - cnt * CNT_SCALE;
        const float mean = (float)(sum / fmax(cnt, 1.0));
        out[i] = sig_std(mean + b_pred[0]);
    }
}

extern "C" void kernel_launch(void* const* d_in, const int* in_sizes, int n_in,
                              void* d_out, int out_size, void* d_ws, size_t ws_size,
                              hipStream_t stream) {
    const float* stu_x    = (const float*)d_in[0];
    const float* item_x   = (const float*)d_in[1];
    const float* conc_x   = (const float*)d_in[2];
    const float* W_stu    = (const float*)d_in[3];
    const float* b_stu    = (const float*)d_in[4];
    const float* W_item   = (const float*)d_in[5];
    const float* b_item   = (const float*)d_in[6];
    const float* W_pred   = (const float*)d_in[7];
    const float* b_pred   = (const float*)d_in[8];
    const int* stu_track  = (const int*)d_in[9];
    const int* item_index = (const int*)d_in[10];
    const int* conc_index = (const int*)d_in[11];
    const int* mean_index = (const int*)d_in[12];

    const int NS = in_sizes[0] / CDIM;
    const int NI = in_sizes[1] / CDIM;
    const int NC = in_sizes[2] / CDIM;
    const int E  = in_sizes[9];
    const int M  = out_size;

    // workspace layout (all pieces 16B-aligned)
    double* sc     = (double*)d_ws;              // [M] packed (sum + cnt*2^24)
    u16* Wstu_bf   = (u16*)(sc + M);             // Wstu_bf || Witem_bf contiguous
    u16* Witem_bf  = Wstu_bf + CDIM * CDIM;
    u16* stu_p     = Witem_bf + CDIM * CDIM;
    u16* item_p    = stu_p  + (size_t)NS * CDIM;
    u16* conc_cat  = item_p + (size_t)NI * CDIM; // [NC][256]: exp2 stu | item side
    int4* idx4     = (int4*)(conc_cat + (size_t)NC * 256);
    u32* lhists    = (u32*)(idx4 + E);           // [HBLK][NBUCK]
    u32* tot       = lhists + (size_t)HBLK * NBUCK;
    u32* cursor    = tot + NBUCK;

    const int nZero4 = (int)(((size_t)M * sizeof(double)) / 16);
    prep_kernel<<<512, 256, 0, stream>>>(W_stu, W_item, (u32*)Wstu_bf,
                                         (float4*)sc, nZero4);

    hist_kernel<<<HBLK, 256, 0, stream>>>(stu_track, lhists, E);

    reduce_kernel<<<NBUCK / 256, 256, 0, stream>>>(lhists, tot);

    scan_kernel<<<1, 256, 0, stream>>>(tot, cursor);

    scatter_kernel<<<HBLK, 256, 0, stream>>>(stu_track, item_index, conc_index,
                                             mean_index, cursor, lhists, idx4, E);

    const int T0 = (NS + 31) / 32, T1 = (NI + 31) / 32, T2 = (NC + 31) / 32;
    const int totalWaves = T0 + T1 + 2 * T2;
    proj4_kernel<<<(totalWaves + 3) / 4, 256, 0, stream>>>(
        stu_x, item_x, conc_x, Wstu_bf, Witem_bf, b_stu, b_item,
        stu_p, item_p, conc_cat, NS, NI, NC);

    edge_kernel<<<512, 256, 0, stream>>>(stu_p, item_p, conc_cat,
                                         idx4, W_pred, sc, E);

    final_kernel<<<(M + 255) / 256, 256, 0, stream>>>(sc, b_pred, (float*)d_out, M);
}

// Round 12
// 247.337 us; speedup vs baseline: 1.9598x; 1.0627x over previous
//
#include <hip/hip_runtime.h>

typedef unsigned short u16;
typedef unsigned int   u32;

typedef short short8 __attribute__((ext_vector_type(8)));
typedef float floatx4 __attribute__((ext_vector_type(4)));

#define CDIM 128
#define K_NEG_LOG2E -1.4426950408889634f
#define CNT_SCALE 16777216.0   // 2^24: packs (sum, count) into one f64
#define NBUCK 4096             // si>>4 buckets (NS=50K -> 3125 used)
#define HBLK 128               // histogram / scatter blocks

__device__ __forceinline__ float bf2f_lo(u32 h) {
    union { u32 u; float f; } v; v.u = h << 16; return v.f;
}
__device__ __forceinline__ float bf2f_hi(u32 h) {
    union { u32 u; float f; } v; v.u = h & 0xffff0000u; return v.f;
}
__device__ __forceinline__ u16 f2bf(float f) {
    union { float f; u32 u; } v; v.f = f;
    u32 u = v.u;
    return (u16)((u + 0x7FFFu + ((u >> 16) & 1u)) >> 16);  // RNE
}
__device__ __forceinline__ float sig_std(float x) {
    return __builtin_amdgcn_rcpf(1.0f + __builtin_amdgcn_exp2f(x * K_NEG_LOG2E));
}
// sort key: stu-row group of 16 -> contiguous edges share a tiny stu footprint
__device__ __forceinline__ u32 skey(u32 si) { return si >> 4; }

// Fused: zero f64 accumulators + weight cvt + per-block LDS histogram.
__global__ __launch_bounds__(256) void prep_kernel(
    const float* __restrict__ Wstu, const float* __restrict__ Witem,
    u32* __restrict__ Wbf_pair, float4* __restrict__ zero4, int nZero4,
    const int* __restrict__ stu_track, u32* __restrict__ lhists, int E)
{
    __shared__ u32 h[NBUCK];
    for (int k = threadIdx.x; k < NBUCK; k += 256) h[k] = 0;

    const int tid = blockIdx.x * blockDim.x + threadIdx.x;
    const int stride = gridDim.x * blockDim.x;
    for (int i = tid; i < 16384; i += stride) {
        const float* W = (i & 8192) ? (Witem - 16384) : Wstu;
        const int j = i * 2;
        u32 lo = f2bf(W[j]     * K_NEG_LOG2E);
        u32 hi = f2bf(W[j + 1] * K_NEG_LOG2E);
        Wbf_pair[i] = lo | (hi << 16);
    }
    const float4 z = {0.f, 0.f, 0.f, 0.f};
    for (int i = tid; i < nZero4; i += stride) zero4[i] = z;

    __syncthreads();
    const int chunk = (E + gridDim.x - 1) / gridDim.x;
    const int s = blockIdx.x * chunk;
    const int e = min(E, s + chunk);
    for (int i = s + threadIdx.x; i < e; i += 256)
        atomicAdd(&h[skey((u32)stu_track[i])], 1u);
    __syncthreads();
    u32* out = lhists + (size_t)blockIdx.x * NBUCK;
    for (int k = threadIdx.x; k < NBUCK; k += 256) out[k] = h[k];
}

// One WAVE per bucket: shuffle-scan the 128 per-block counts into exclusive
// over-block offsets (in place) + bucket total. 64x more parallel than the
// one-thread-per-bucket serial chain (R11's 25 us tiny-launch trap).
__global__ __launch_bounds__(256) void reduce_kernel(
    u32* __restrict__ lhists, u32* __restrict__ tot)
{
    const int lane = threadIdx.x & 63;
    const int k = (int)((blockIdx.x * blockDim.x + threadIdx.x) >> 6);
    if (k >= NBUCK) return;

    u32* p0 = lhists + (size_t)lane * NBUCK + k;          // block b = lane
    u32* p1 = lhists + (size_t)(64 + lane) * NBUCK + k;   // block b = 64+lane
    const u32 o0 = *p0, o1 = *p1;

    u32 v0 = o0, v1 = o1;
#pragma unroll
    for (int off = 1; off < 64; off <<= 1) {
        u32 n = __shfl_up(v0, off, 64);
        if (lane >= off) v0 += n;
    }
    const u32 T0 = __shfl(v0, 63, 64);
#pragma unroll
    for (int off = 1; off < 64; off <<= 1) {
        u32 n = __shfl_up(v1, off, 64);
        if (lane >= off) v1 += n;
    }
    const u32 T1 = __shfl(v1, 63, 64);

    *p0 = v0 - o0;              // exclusive over blocks
    *p1 = T0 + v1 - o1;
    if (lane == 0) tot[k] = T0 + T1;
}

// Single block: exclusive prefix over NBUCK totals -> cursor.
__global__ __launch_bounds__(256) void scan_kernel(
    const u32* __restrict__ tot, u32* __restrict__ cursor)
{
    __shared__ u32 psum[256];
    const int t = threadIdx.x;
    const int PER = NBUCK / 256;   // 16
    u32 loc[PER];
    u32 s = 0;
#pragma unroll
    for (int j = 0; j < PER; ++j) { loc[j] = tot[t * PER + j]; s += loc[j]; }
    psum[t] = s;
    __syncthreads();
    for (int off = 1; off < 256; off <<= 1) {
        u32 add = (t >= off) ? psum[t - off] : 0;
        __syncthreads();
        psum[t] += add;
        __syncthreads();
    }
    u32 run = (t > 0) ? psum[t - 1] : 0;
#pragma unroll
    for (int j = 0; j < PER; ++j) {
        cursor[t * PER + j] = run;
        run += loc[j];
    }
}

// Counting-sort scatter, fully deterministic (zero global atomics):
// base = cursor[k] + lhists_excl[block][k]; within-block order via LDS atomics.
__global__ __launch_bounds__(256) void scatter_kernel(
    const int* __restrict__ stu_track, const int* __restrict__ item_index,
    const int* __restrict__ conc_index, const int* __restrict__ mean_index,
    const u32* __restrict__ cursor, const u32* __restrict__ lhists,
    int4* __restrict__ idx4, int E)
{
    __shared__ u32 lbase[NBUCK];
    const u32* myoff = lhists + (size_t)blockIdx.x * NBUCK;
    for (int k = threadIdx.x; k < NBUCK; k += blockDim.x)
        lbase[k] = cursor[k] + myoff[k];
    __syncthreads();
    const int chunk = (E + gridDim.x - 1) / gridDim.x;
    const int start = blockIdx.x * chunk;
    const int end   = min(E, start + chunk);
    for (int e = start + threadIdx.x; e < end; e += blockDim.x) {
        const u32 si = (u32)stu_track[e];
        const u32 pos = atomicAdd(&lbase[skey(si)], 1u);
        int4 t;
        t.x = (int)(si << 8);              // 256 B rows
        t.y = item_index[e] << 8;          // 256 B rows
        t.z = conc_index[e] << 9;          // 512 B rows (cat)
        t.w = mean_index[e] << 3;          // f64 slots
        idx4[pos] = t;
    }
}

// One wave computes a 32-row tile; stores exp2(proj + bias) in bf16.
__device__ __forceinline__ void proj_tile32(
    const float* __restrict__ X, const u16* __restrict__ Wbf,
    const float* __restrict__ bias, u16* __restrict__ out,
    int nrows, int ostride, int ooff, int row0, int lane)
{
    const int m = lane & 15;   // A-row / B-col / D-col
    const int g = lane >> 4;   // k-quad

    short8 a[2][4];
#pragma unroll
    for (int t = 0; t < 2; ++t) {
        int arow = row0 + t * 16 + m;
        if (arow >= nrows) arow = nrows - 1;   // clamp; stores masked below
        const float* xrow = X + (size_t)arow * CDIM;
#pragma unroll
        for (int s = 0; s < 4; ++s) {
            float4 f0 = *(const float4*)(xrow + s * 32 + g * 8);
            float4 f1 = *(const float4*)(xrow + s * 32 + g * 8 + 4);
            a[t][s][0] = (short)f2bf(f0.x); a[t][s][1] = (short)f2bf(f0.y);
            a[t][s][2] = (short)f2bf(f0.z); a[t][s][3] = (short)f2bf(f0.w);
            a[t][s][4] = (short)f2bf(f1.x); a[t][s][5] = (short)f2bf(f1.y);
            a[t][s][6] = (short)f2bf(f1.z); a[t][s][7] = (short)f2bf(f1.w);
        }
    }

#pragma unroll
    for (int ct = 0; ct < 8; ++ct) {
        const u16* wrow = Wbf + (size_t)(ct * 16 + m) * CDIM;
        floatx4 acc0 = {0.f, 0.f, 0.f, 0.f};
        floatx4 acc1 = {0.f, 0.f, 0.f, 0.f};
#pragma unroll
        for (int s = 0; s < 4; ++s) {
            short8 b = *(const short8*)(wrow + s * 32 + g * 8);
            acc0 = __builtin_amdgcn_mfma_f32_16x16x32_bf16(a[0][s], b, acc0, 0, 0, 0);
            acc1 = __builtin_amdgcn_mfma_f32_16x16x32_bf16(a[1][s], b, acc1, 0, 0, 0);
        }
        const int col = ct * 16 + m;           // D: col = lane&15
        const float badd = bias ? bias[col] * K_NEG_LOG2E : 0.f;
#pragma unroll
        for (int i = 0; i < 4; ++i) {
            int r0 = row0 + g * 4 + i;         // D: row = (lane>>4)*4 + reg
            if (r0 < nrows)
                out[(size_t)r0 * ostride + ooff + col] =
                    f2bf(__builtin_amdgcn_exp2f(acc0[i] + badd));
            int r1 = r0 + 16;
            if (r1 < nrows)
                out[(size_t)r1 * ostride + ooff + col] =
                    f2bf(__builtin_amdgcn_exp2f(acc1[i] + badd));
        }
    }
}

// All four projections in one launch; wave-uniform segment select.
__global__ __launch_bounds__(256) void proj4_kernel(
    const float* __restrict__ stu_x, const float* __restrict__ item_x,
    const float* __restrict__ conc_x,
    const u16* __restrict__ Wstu_bf, const u16* __restrict__ Witem_bf,
    const float* __restrict__ b_stu, const float* __restrict__ b_item,
    u16* __restrict__ stu_p, u16* __restrict__ item_p, u16* __restrict__ conc_cat,
    int NS, int NI, int NC)
{
    const int lane = threadIdx.x & 63;
    int w = blockIdx.x * 4 + (threadIdx.x >> 6);
    const int T0 = (NS + 31) / 32, T1 = (NI + 31) / 32, T2 = (NC + 31) / 32;

    if (w < T0) { proj_tile32(stu_x, Wstu_bf, nullptr, stu_p, NS, 128, 0, w * 32, lane); return; }
    w -= T0;
    if (w < T1) { proj_tile32(item_x, Witem_bf, nullptr, item_p, NI, 128, 0, w * 32, lane); return; }
    w -= T1;
    if (w < T2) { proj_tile32(conc_x, Wstu_bf, b_stu, conc_cat, NC, 256, 0, w * 32, lane); return; }
    w -= T2;
    if (w < T2) { proj_tile32(conc_x, Witem_bf, b_item, conc_cat, NC, 256, 128, w * 32, lane); return; }
}

// 16 lanes per edge, 4 edges per wave. idx4 si-sorted; contiguous chunk per
// wave (~31 quads -> ~1.5 KB stu window, L1-hot). 2048 blocks = 8 blocks/CU
// (single residency round at VGPR~40) for latency hiding.
__global__ __launch_bounds__(256) void edge_kernel(
    const u16* __restrict__ stu_p, const u16* __restrict__ item_p,
    const u16* __restrict__ conc_cat,
    const int4* __restrict__ idx4,     // byte offsets {stu, item, conc, mean}
    const float* __restrict__ w_pred,
    double* __restrict__ sc, int E)
{
    const int lane = threadIdx.x & 63;
    const int sub  = lane & 15;      // position within edge
    const int g    = lane >> 4;      // edge within quad
    const int waveId = (int)((blockIdx.x * blockDim.x + threadIdx.x) >> 6);
    const int nWavesTot = (int)((gridDim.x * blockDim.x) >> 6);

    const float4 wA = ((const float4*)w_pred)[sub * 2];
    const float4 wB = ((const float4*)w_pred)[sub * 2 + 1];
    float2 w2[4];
    w2[0] = make_float2(wA.x, wA.y); w2[1] = make_float2(wA.z, wA.w);
    w2[2] = make_float2(wB.x, wB.y); w2[3] = make_float2(wB.z, wB.w);
    const u32 lane_off = (u32)sub * 16;

    const int nQuads = (E + 3) >> 2;
    const int chunk  = (nQuads + nWavesTot - 1) / nWavesTot;
    int q = waveId * chunk;
    const int qEnd = min(nQuads, q + chunk);
    if (q >= qEnd) return;

    auto ldidx = [&](int qq) -> int4 {
        int e = qq * 4 + g;
        e = (e < E) ? e : (E - 1);
        return idx4[e];
    };
    auto compute = [&](const uint4& sv, const uint4& iv,
                       const uint4& ca, const uint4& cb,
                       int mw, int qq) {
        const u32 su[4] = {sv.x, sv.y, sv.z, sv.w};
        const u32 iu[4] = {iv.x, iv.y, iv.z, iv.w};
        const u32 au[4] = {ca.x, ca.y, ca.z, ca.w};
        const u32 bu[4] = {cb.x, cb.y, cb.z, cb.w};
        const float2 one = make_float2(1.f, 1.f);
        float2 vacc = make_float2(0.f, 0.f);
#pragma unroll
        for (int j = 0; j < 4; ++j) {
            float2 A  = make_float2(bf2f_lo(au[j]), bf2f_hi(au[j]));
            float2 Sx = make_float2(bf2f_lo(su[j]), bf2f_hi(su[j]));
            float2 B  = make_float2(bf2f_lo(bu[j]), bf2f_hi(bu[j]));
            float2 Ix = make_float2(bf2f_lo(iu[j]), bf2f_hi(iu[j]));
            float2 ea = A * Sx;                    // v_pk_mul_f32
            float2 eb = B * Ix;
            float2 den = (ea + one) * (eb + one);  // (1+ea)(1+eb)
            float2 num = eb - ea;
            float2 rd = make_float2(__builtin_amdgcn_rcpf(den.x),
                                    __builtin_amdgcn_rcpf(den.y));
            vacc += (num * rd) * w2[j];
        }
        float v = vacc.x + vacc.y;
        v += __shfl_xor(v, 1, 64);
        v += __shfl_xor(v, 2, 64);
        v += __shfl_xor(v, 4, 64);
        v += __shfl_xor(v, 8, 64);
        if (sub == 0 && (qq * 4 + g) < E)
            atomicAdd((double*)((char*)sc + (u32)mw), (double)v + CNT_SCALE);
    };

#define GATH(I_, sv_, iv_, ca_, cb_) { \
        sv_ = *(const uint4*)((const char*)stu_p  + ((u32)(I_).x + lane_off)); \
        iv_ = *(const uint4*)((const char*)item_p + ((u32)(I_).y + lane_off)); \
        const char* cp_ = (const char*)conc_cat + ((u32)(I_).z + lane_off); \
        ca_ = *(const uint4*)cp_; cb_ = *(const uint4*)(cp_ + 256); }

#define STEP(DA, DB, IA, IB, IC) { \
        GATH(I##IB, sv##DB, iv##DB, ca##DB, cb##DB); \
        I##IC = ldidx(q + 2); \
        __builtin_amdgcn_sched_barrier(0x7); \
        compute(sv##DA, iv##DA, ca##DA, cb##DA, I##IA.w, q); \
        q += 1; \
        if (q >= qEnd) break; }

    // preamble
    int4 I0 = ldidx(q), I1 = ldidx(q + 1), I2, I3;
    uint4 sv0, iv0, ca0, cb0, sv1, iv1, ca1, cb1;
    GATH(I0, sv0, iv0, ca0, cb0);

    for (;;) {
        STEP(0, 1, 0, 1, 2)
        STEP(1, 0, 1, 2, 3)
        STEP(0, 1, 2, 3, 0)
        STEP(1, 0, 3, 0, 1)
    }
#undef STEP
#undef GATH
}

__global__ __launch_bounds__(256) void final_kernel(
    const double* __restrict__ sc,
    const float* __restrict__ b_pred, float* __restrict__ out, int M)
{
    const int i = blockIdx.x * blockDim.x + threadIdx.x;
    if (i < M) {
        const double acc = sc[i];
        const double cnt = rint(acc * (1.0 / CNT_SCALE));   // |sum| << 2^23
        const double sum = acc - cnt * CNT_SCALE;
        const float mean = (float)(sum / fmax(cnt, 1.0));
        out[i] = sig_std(mean + b_pred[0]);
    }
}

extern "C" void kernel_launch(void* const* d_in, const int* in_sizes, int n_in,
                              void* d_out, int out_size, void* d_ws, size_t ws_size,
                              hipStream_t stream) {
    const float* stu_x    = (const float*)d_in[0];
    const float* item_x   = (const float*)d_in[1];
    const float* conc_x   = (const float*)d_in[2];
    const float* W_stu    = (const float*)d_in[3];
    const float* b_stu    = (const float*)d_in[4];
    const float* W_item   = (const float*)d_in[5];
    const float* b_item   = (const float*)d_in[6];
    const float* W_pred   = (const float*)d_in[7];
    const float* b_pred   = (const float*)d_in[8];
    const int* stu_track  = (const int*)d_in[9];
    const int* item_index = (const int*)d_in[10];
    const int* conc_index = (const int*)d_in[11];
    const int* mean_index = (const int*)d_in[12];

    const int NS = in_sizes[0] / CDIM;
    const int NI = in_sizes[1] / CDIM;
    const int NC = in_sizes[2] / CDIM;
    const int E  = in_sizes[9];
    const int M  = out_size;

    // workspace layout (all pieces 16B-aligned)
    double* sc     = (double*)d_ws;              // [M] packed (sum + cnt*2^24)
    u16* Wstu_bf   = (u16*)(sc + M);             // Wstu_bf || Witem_bf contiguous
    u16* Witem_bf  = Wstu_bf + CDIM * CDIM;
    u16* stu_p     = Witem_bf + CDIM * CDIM;
    u16* item_p    = stu_p  + (size_t)NS * CDIM;
    u16* conc_cat  = item_p + (size_t)NI * CDIM; // [NC][256]: exp2 stu | item side
    int4* idx4     = (int4*)(conc_cat + (size_t)NC * 256);
    u32* lhists    = (u32*)(idx4 + E);           // [HBLK][NBUCK]
    u32* tot       = lhists + (size_t)HBLK * NBUCK;
    u32* cursor    = tot + NBUCK;

    const int nZero4 = (int)(((size_t)M * sizeof(double)) / 16);
    prep_kernel<<<HBLK, 256, 0, stream>>>(W_stu, W_item, (u32*)Wstu_bf,
                                          (float4*)sc, nZero4,
                                          stu_track, lhists, E);

    reduce_kernel<<<NBUCK / 4, 256, 0, stream>>>(lhists, tot);

    scan_kernel<<<1, 256, 0, stream>>>(tot, cursor);

    scatter_kernel<<<HBLK, 256, 0, stream>>>(stu_track, item_index, conc_index,
                                             mean_index, cursor, lhists, idx4, E);

    const int T0 = (NS + 31) / 32, T1 = (NI + 31) / 32, T2 = (NC + 31) / 32;
    const int totalWaves = T0 + T1 + 2 * T2;
    proj4_kernel<<<(totalWaves + 3) / 4, 256, 0, stream>>>(
        stu_x, item_x, conc_x, Wstu_bf, Witem_bf, b_stu, b_item,
        stu_p, item_p, conc_cat, NS, NI, NC);

    edge_kernel<<<2048, 256, 0, stream>>>(stu_p, item_p, conc_cat,
                                          idx4, W_pred, sc, E);

    final_kernel<<<(M + 255) / 256, 256, 0, stream>>>(sc, b_pred, (float*)d_out, M);
}